// Round 1
// baseline (846.656 us; speedup 1.0000x reference)
//
#include <hip/hip_runtime.h>
#include <cstdint>
#include <cstddef>

// Problem constants (G=2,S=1024,D=2048,E=8,K=2)
#define DHID 2048
#define NEXP 8
#define NTOK 2048            // G*S tokens
#define NPAIR 4096           // NTOK*K routed pairs
#define NROWS 6144           // NPAIR + NTOK (shared expert appended)

typedef __attribute__((ext_vector_type(8))) __bf16 bf16x8;
typedef __attribute__((ext_vector_type(4))) __bf16 bf16x4v;
typedef __attribute__((ext_vector_type(4))) float f32x4;

typedef __attribute__((address_space(3))) void lds_void;
typedef __attribute__((address_space(1))) void gbl_void;

__device__ __forceinline__ void gload16(const void* g, void* l) {
  __builtin_amdgcn_global_load_lds((gbl_void*)g, (lds_void*)l, 16, 0, 0);
}

// ---------------- routing: bucket pairs by expert, append shared pseudo-expert ----
__global__ void route_kernel(const int* __restrict__ idx, const float* __restrict__ wts,
                             int* __restrict__ tok_id, float* __restrict__ tok_w,
                             int* __restrict__ cnts, int* __restrict__ offs) {
  __shared__ int c[NEXP];
  __shared__ int cur[NEXP];
  const int t = threadIdx.x;
  if (t < NEXP) c[t] = 0;
  __syncthreads();
  for (int p = t; p < NPAIR; p += 256) atomicAdd(&c[idx[p]], 1);
  __syncthreads();
  if (t == 0) {
    int run = 0;
    for (int e = 0; e < NEXP; ++e) { cur[e] = run; offs[e] = run; cnts[e] = c[e]; run += c[e]; }
    offs[NEXP] = NPAIR; cnts[NEXP] = NTOK;
  }
  __syncthreads();
  for (int p = t; p < NPAIR; p += 256) {
    const int e = idx[p];
    const int slot = atomicAdd(&cur[e], 1);
    tok_id[slot] = p >> 1;          // K=2: token = pair/2 (flat g*S+s)
    tok_w[slot] = wts[p];
  }
  for (int i = t; i < NTOK; i += 256) { tok_id[NPAIR + i] = i; tok_w[NPAIR + i] = 1.0f; }
}

// ---------------- cast x f32 -> bf16 ----------------
__global__ void cast_kernel(const float4* __restrict__ x, bf16x4v* __restrict__ xb) {
  const int i = blockIdx.x * 256 + threadIdx.x;
  const float4 v = x[i];
  bf16x4v o;
  o[0] = (__bf16)v.x; o[1] = (__bf16)v.y; o[2] = (__bf16)v.z; o[3] = (__bf16)v.w;
  xb[i] = o;
}

// ---------------- fused gate+up grouped GEMM + SiLU ----------------
// A: gathered token rows (bf16), B: f32 [N,K] weights (converted to bf16 at frag read)
__global__ __launch_bounds__(256) void gateup_kernel(
    const __bf16* __restrict__ xb,
    const float* __restrict__ gw, const float* __restrict__ uw,
    const float* __restrict__ sgw, const float* __restrict__ suw,
    __bf16* __restrict__ act,
    const int* __restrict__ tok_id,
    const int* __restrict__ cnts, const int* __restrict__ offs) {
  const int e = blockIdx.z;
  const int cnt = cnts[e];
  const int m0 = blockIdx.y * 128;
  if (m0 >= cnt) return;
  const int n0 = blockIdx.x * 128;
  const int off = offs[e];
  const float* Bg = (e < NEXP) ? gw + (size_t)e * DHID * DHID : sgw;
  const float* Bu = (e < NEXP) ? uw + (size_t)e * DHID * DHID : suw;

  __shared__ __align__(16) char sA[128 * 32 * 2];     // bf16 [128][32], 16B chunks XOR-swizzled
  __shared__ __align__(16) char sBg[128 * 32 * 4];    // f32  [128][32], 16B chunks XOR-swizzled
  __shared__ __align__(16) char sBu[128 * 32 * 4];

  const int tid = threadIdx.x;
  const int lane = tid & 63;
  const int wv = tid >> 6;
  const int mw = (wv >> 1) * 64;
  const int nw = (wv & 1) * 64;
  const int q4 = lane >> 4;
  const int ln = lane & 15;

  // staging: A chunks q = tid, tid+256 -> row q>>2, swizzled part (q&3)^((q>>3)&3)
  const int ra = tid >> 2;
  const int pa = (tid & 3) ^ ((tid >> 3) & 3);
  const int r0 = m0 + ra, r1 = m0 + ra + 64;
  const int t0 = tok_id[off + (r0 < cnt ? r0 : cnt - 1)];
  const int t1 = tok_id[off + (r1 < cnt ? r1 : cnt - 1)];
  const char* gA0 = (const char*)(xb + (size_t)t0 * DHID) + pa * 16;
  const char* gA1 = (const char*)(xb + (size_t)t1 * DHID) + pa * 16;

  // B chunks q = tid + j*256 -> row q>>3, swizzled part (q&7)^((q>>3)&7)
  const int rb = tid >> 3;
  const int pb = (tid & 7) ^ ((tid >> 3) & 7);
  const char* gBg0 = (const char*)(Bg + (size_t)(n0 + rb) * DHID) + pb * 16;
  const char* gBu0 = (const char*)(Bu + (size_t)(n0 + rb) * DHID) + pb * 16;
  const size_t bstep = (size_t)32 * DHID * 4;

  f32x4 accg[4][4], accu[4][4];
  const f32x4 vz = {0.f, 0.f, 0.f, 0.f};
#pragma unroll
  for (int i = 0; i < 4; ++i)
#pragma unroll
    for (int j = 0; j < 4; ++j) { accg[i][j] = vz; accu[i][j] = vz; }

  for (int kt = 0; kt < DHID; kt += 32) {
    gload16(gA0 + (size_t)kt * 2, sA + tid * 16);
    gload16(gA1 + (size_t)kt * 2, sA + (tid + 256) * 16);
#pragma unroll
    for (int j = 0; j < 4; ++j) {
      gload16(gBg0 + j * bstep + (size_t)kt * 4, sBg + (tid + j * 256) * 16);
      gload16(gBu0 + j * bstep + (size_t)kt * 4, sBu + (tid + j * 256) * 16);
    }
    __syncthreads();

    bf16x8 af[4];
#pragma unroll
    for (int im = 0; im < 4; ++im) {
      const int r = mw + im * 16 + ln;
      af[im] = *(const bf16x8*)(sA + ((r * 4 + (q4 ^ ((r >> 1) & 3))) << 4));
    }
#pragma unroll
    for (int in_ = 0; in_ < 4; ++in_) {
      const int r = nw + in_ * 16 + ln;
      const int sw = r & 7;
      const float4 g0 = *(const float4*)(sBg + ((r * 8 + ((q4 * 2) ^ sw)) << 4));
      const float4 g1 = *(const float4*)(sBg + ((r * 8 + ((q4 * 2 + 1) ^ sw)) << 4));
      const float4 u0 = *(const float4*)(sBu + ((r * 8 + ((q4 * 2) ^ sw)) << 4));
      const float4 u1 = *(const float4*)(sBu + ((r * 8 + ((q4 * 2 + 1) ^ sw)) << 4));
      bf16x8 bg, bu;
      bg[0] = (__bf16)g0.x; bg[1] = (__bf16)g0.y; bg[2] = (__bf16)g0.z; bg[3] = (__bf16)g0.w;
      bg[4] = (__bf16)g1.x; bg[5] = (__bf16)g1.y; bg[6] = (__bf16)g1.z; bg[7] = (__bf16)g1.w;
      bu[0] = (__bf16)u0.x; bu[1] = (__bf16)u0.y; bu[2] = (__bf16)u0.z; bu[3] = (__bf16)u0.w;
      bu[4] = (__bf16)u1.x; bu[5] = (__bf16)u1.y; bu[6] = (__bf16)u1.z; bu[7] = (__bf16)u1.w;
#pragma unroll
      for (int im = 0; im < 4; ++im) {
        accg[im][in_] = __builtin_amdgcn_mfma_f32_16x16x32_bf16(af[im], bg, accg[im][in_], 0, 0, 0);
        accu[im][in_] = __builtin_amdgcn_mfma_f32_16x16x32_bf16(af[im], bu, accu[im][in_], 0, 0, 0);
      }
    }
    __syncthreads();
  }

  // epilogue: act = silu(gate) * up -> bf16
#pragma unroll
  for (int im = 0; im < 4; ++im) {
#pragma unroll
    for (int r = 0; r < 4; ++r) {
      const int row = mw + im * 16 + q4 * 4 + r;
      if (m0 + row < cnt) {
        __bf16* dst = act + (size_t)(off + m0 + row) * DHID + n0 + nw + ln;
#pragma unroll
        for (int in_ = 0; in_ < 4; ++in_) {
          const float gg = accg[im][in_][r];
          const float uu = accu[im][in_][r];
          const float a = (gg / (1.0f + __expf(-gg))) * uu;
          dst[in_ * 16] = (__bf16)a;
        }
      }
    }
  }
}

// ---------------- down grouped GEMM, weighted atomic scatter ----------------
__global__ __launch_bounds__(256) void down_kernel(
    const __bf16* __restrict__ act,
    const float* __restrict__ dw, const float* __restrict__ sdw,
    float* __restrict__ out,
    const int* __restrict__ tok_id, const float* __restrict__ tok_w,
    const int* __restrict__ cnts, const int* __restrict__ offs) {
  const int e = blockIdx.z;
  const int cnt = cnts[e];
  const int m0 = blockIdx.y * 128;
  if (m0 >= cnt) return;
  const int n0 = blockIdx.x * 128;
  const int off = offs[e];
  const float* B = (e < NEXP) ? dw + (size_t)e * DHID * DHID : sdw;

  __shared__ __align__(16) char sA[128 * 32 * 2];
  __shared__ __align__(16) char sB[128 * 32 * 4];

  const int tid = threadIdx.x;
  const int lane = tid & 63;
  const int wv = tid >> 6;
  const int mw = (wv >> 1) * 64;
  const int nw = (wv & 1) * 64;
  const int q4 = lane >> 4;
  const int ln = lane & 15;

  const int ra = tid >> 2;
  const int pa = (tid & 3) ^ ((tid >> 3) & 3);
  const char* gA0 = (const char*)(act + (size_t)(off + m0 + ra) * DHID) + pa * 16;
  const char* gA1 = gA0 + (size_t)64 * DHID * 2;

  const int rb = tid >> 3;
  const int pb = (tid & 7) ^ ((tid >> 3) & 7);
  const char* gB0 = (const char*)(B + (size_t)(n0 + rb) * DHID) + pb * 16;
  const size_t bstep = (size_t)32 * DHID * 4;

  f32x4 acc[4][4];
  const f32x4 vz = {0.f, 0.f, 0.f, 0.f};
#pragma unroll
  for (int i = 0; i < 4; ++i)
#pragma unroll
    for (int j = 0; j < 4; ++j) acc[i][j] = vz;

  for (int kt = 0; kt < DHID; kt += 32) {
    gload16(gA0 + (size_t)kt * 2, sA + tid * 16);
    gload16(gA1 + (size_t)kt * 2, sA + (tid + 256) * 16);
#pragma unroll
    for (int j = 0; j < 4; ++j)
      gload16(gB0 + j * bstep + (size_t)kt * 4, sB + (tid + j * 256) * 16);
    __syncthreads();

    bf16x8 af[4];
#pragma unroll
    for (int im = 0; im < 4; ++im) {
      const int r = mw + im * 16 + ln;
      af[im] = *(const bf16x8*)(sA + ((r * 4 + (q4 ^ ((r >> 1) & 3))) << 4));
    }
#pragma unroll
    for (int in_ = 0; in_ < 4; ++in_) {
      const int r = nw + in_ * 16 + ln;
      const int sw = r & 7;
      const float4 b0 = *(const float4*)(sB + ((r * 8 + ((q4 * 2) ^ sw)) << 4));
      const float4 b1 = *(const float4*)(sB + ((r * 8 + ((q4 * 2 + 1) ^ sw)) << 4));
      bf16x8 bb;
      bb[0] = (__bf16)b0.x; bb[1] = (__bf16)b0.y; bb[2] = (__bf16)b0.z; bb[3] = (__bf16)b0.w;
      bb[4] = (__bf16)b1.x; bb[5] = (__bf16)b1.y; bb[6] = (__bf16)b1.z; bb[7] = (__bf16)b1.w;
#pragma unroll
      for (int im = 0; im < 4; ++im)
        acc[im][in_] = __builtin_amdgcn_mfma_f32_16x16x32_bf16(af[im], bb, acc[im][in_], 0, 0, 0);
    }
    __syncthreads();
  }

#pragma unroll
  for (int im = 0; im < 4; ++im) {
#pragma unroll
    for (int r = 0; r < 4; ++r) {
      const int row = mw + im * 16 + q4 * 4 + r;
      if (m0 + row < cnt) {
        const int gr = off + m0 + row;
        const int tok = tok_id[gr];
        const float wt = tok_w[gr];
        float* dst = out + (size_t)tok * DHID + n0 + nw + ln;
#pragma unroll
        for (int in_ = 0; in_ < 4; ++in_)
          atomicAdd(dst + in_ * 16, wt * acc[im][in_][r]);
      }
    }
  }
}

extern "C" void kernel_launch(void* const* d_in, const int* in_sizes, int n_in,
                              void* d_out, int out_size, void* d_ws, size_t ws_size,
                              hipStream_t stream) {
  (void)in_sizes; (void)n_in; (void)ws_size;
  const float* x   = (const float*)d_in[0];
  const float* wts = (const float*)d_in[1];
  const int*   idx = (const int*)d_in[2];
  const float* gw  = (const float*)d_in[5];
  const float* uw  = (const float*)d_in[6];
  const float* dwn = (const float*)d_in[7];
  const float* sgw = (const float*)d_in[8];
  const float* suw = (const float*)d_in[9];
  const float* sdw = (const float*)d_in[10];
  float* out = (float*)d_out;

  char* ws = (char*)d_ws;
  // ws layout (needs ~32.1 MiB):
  //   [0, 8MiB)           xb   bf16 [2048][2048]
  //   [8MiB, 32MiB)       act  bf16 [6144][2048]
  //   [32MiB, ...)        tok_id int[6144], tok_w float[6144], cnts int[16], offs int[16]
  __bf16* xb  = (__bf16*)ws;
  __bf16* act = (__bf16*)(ws + ((size_t)8 << 20));
  constexpr size_t ROUTE_OFF = (size_t)8 * 1024 * 1024 + (size_t)NROWS * DHID * 2;
  int*   tok_id = (int*)(ws + ROUTE_OFF);
  float* tok_w  = (float*)(ws + ROUTE_OFF + NROWS * 4);
  int*   cnts   = (int*)(ws + ROUTE_OFF + NROWS * 8);
  int*   offs   = cnts + 16;

  (void)hipMemsetAsync(d_out, 0, (size_t)out_size * sizeof(float), stream);
  route_kernel<<<1, 256, 0, stream>>>(idx, wts, tok_id, tok_w, cnts, offs);
  cast_kernel<<<(NTOK * DHID / 4) / 256, 256, 0, stream>>>((const float4*)x, (bf16x4v*)xb);
  gateup_kernel<<<dim3(16, 32, 9), 256, 0, stream>>>(xb, gw, uw, sgw, suw, act,
                                                     tok_id, cnts, offs);
  down_kernel<<<dim3(16, 32, 9), 256, 0, stream>>>(act, dwn, sdw, out,
                                                   tok_id, tok_w, cnts, offs);
}

// Round 2
// 830.122 us; speedup vs baseline: 1.0199x; 1.0199x over previous
//
#include <hip/hip_runtime.h>
#include <cstdint>
#include <cstddef>

// Problem constants (G=2,S=1024,D=2048,E=8,K=2)
#define DHID 2048
#define NEXP 8
#define NTOK 2048            // G*S tokens
#define NPAIR 4096           // NTOK*K routed pairs
#define NROWS 6144           // NPAIR + NTOK (shared expert appended)
#define MAXTILES 55          // worst-case routed m-tiles (39) + shared (16)
#define DD ((size_t)DHID * DHID)

typedef __attribute__((ext_vector_type(8))) __bf16 bf16x8;
typedef __attribute__((ext_vector_type(4))) float f32x4;

typedef __attribute__((address_space(3))) void lds_void;
typedef __attribute__((address_space(1))) void gbl_void;

__device__ __forceinline__ void gload16(const void* g, void* l) {
  __builtin_amdgcn_global_load_lds((gbl_void*)g, (lds_void*)l, 16, 0, 0);
}

// ---------------- routing: bucket pairs by expert, append shared pseudo-expert,
// ---------------- build (expert, m0) tile list for flattened GEMM grids -------
__global__ void route_kernel(const int* __restrict__ idx, const float* __restrict__ wts,
                             int* __restrict__ tok_id, float* __restrict__ tok_w,
                             int* __restrict__ dst_id,
                             int* __restrict__ cnts, int* __restrict__ offs,
                             int2* __restrict__ tiles) {
  __shared__ int c[NEXP];
  __shared__ int cur[NEXP];
  const int t = threadIdx.x;
  if (t < NEXP) c[t] = 0;
  __syncthreads();
  for (int p = t; p < NPAIR; p += 256) atomicAdd(&c[idx[p]], 1);
  __syncthreads();
  if (t == 0) {
    int run = 0;
    for (int e = 0; e < NEXP; ++e) { cur[e] = run; offs[e] = run; cnts[e] = c[e]; run += c[e]; }
    offs[NEXP] = NPAIR; cnts[NEXP] = NTOK;
    int nt = 0;
    for (int e = 0; e <= NEXP; ++e) {
      const int ce = (e < NEXP) ? c[e] : NTOK;
      for (int m0 = 0; m0 < ce; m0 += 128) { tiles[nt].x = e; tiles[nt].y = m0; ++nt; }
    }
    for (; nt < MAXTILES; ++nt) { tiles[nt].x = -1; tiles[nt].y = 0; }
  }
  __syncthreads();
  for (int p = t; p < NPAIR; p += 256) {
    const int e = idx[p];
    const int slot = atomicAdd(&cur[e], 1);
    tok_id[slot] = p >> 1;          // K=2: token = pair/2 (flat g*S+s)
    tok_w[slot] = wts[p];
    dst_id[slot] = p;               // pair-slot row in combine buffer
  }
  for (int i = t; i < NTOK; i += 256) {
    tok_id[NPAIR + i] = i; tok_w[NPAIR + i] = 1.0f; dst_id[NPAIR + i] = NPAIR + i;
  }
}

// ---------------- f32 -> bf16 cast, 8 elements/thread (16B stores) ------------
__global__ void cast_kernel(const float4* __restrict__ src, bf16x8* __restrict__ dst) {
  const size_t i = (size_t)blockIdx.x * 256 + threadIdx.x;
  const float4 a = src[2 * i];
  const float4 b = src[2 * i + 1];
  bf16x8 o;
  o[0] = (__bf16)a.x; o[1] = (__bf16)a.y; o[2] = (__bf16)a.z; o[3] = (__bf16)a.w;
  o[4] = (__bf16)b.x; o[5] = (__bf16)b.y; o[6] = (__bf16)b.z; o[7] = (__bf16)b.w;
  dst[i] = o;
}

// ---------------- fused gate+up grouped GEMM + SiLU ---------------------------
// BT = __bf16 (pre-cast weights, 9 experts packed, sgw/suw=null) or
// BT = float  (raw weights, expert 8 comes from sgw/suw)
template <typename BT>
__global__ __launch_bounds__(256) void gateup_kernel(
    const __bf16* __restrict__ xb,
    const BT* __restrict__ gwAll, const BT* __restrict__ uwAll,
    const BT* __restrict__ sgw, const BT* __restrict__ suw,
    __bf16* __restrict__ act,
    const int* __restrict__ tok_id,
    const int* __restrict__ cnts, const int* __restrict__ offs,
    const int2* __restrict__ tiles) {
  const int2 tl = tiles[blockIdx.y];
  const int e = tl.x;
  if (e < 0) return;
  const int m0 = tl.y;
  const int cnt = cnts[e];
  const int n0 = blockIdx.x * 128;
  const int off = offs[e];
  const BT* Bg; const BT* Bu;
  if (e < NEXP || sgw == nullptr) { Bg = gwAll + (size_t)e * DD; Bu = uwAll + (size_t)e * DD; }
  else { Bg = sgw; Bu = suw; }

  __shared__ __align__(16) char sA[128 * 32 * 2];               // bf16 [128][32]
  __shared__ __align__(16) char sBg[128 * 32 * sizeof(BT)];
  __shared__ __align__(16) char sBu[128 * 32 * sizeof(BT)];

  const int tid = threadIdx.x;
  const int lane = tid & 63;
  const int wv = tid >> 6;
  const int mw = (wv >> 1) * 64;
  const int nw = (wv & 1) * 64;
  const int q4 = lane >> 4;
  const int ln = lane & 15;

  // A staging: chunk q = tid, tid+256 -> row q>>2, global part (q&3)^((q>>3)&3)
  const int ra = tid >> 2;
  const int pa = (tid & 3) ^ ((tid >> 3) & 3);
  const int r0 = m0 + ra, r1 = r0 + 64;
  const int t0 = tok_id[off + (r0 < cnt ? r0 : cnt - 1)];
  const int t1 = tok_id[off + (r1 < cnt ? r1 : cnt - 1)];
  const char* gA0 = (const char*)(xb + (size_t)t0 * DHID) + pa * 16;
  const char* gA1 = (const char*)(xb + (size_t)t1 * DHID) + pa * 16;

  // B staging constants
  const int rb4 = tid >> 2;                         // bf16 path
  const int pb4 = (tid & 3) ^ ((tid >> 3) & 3);
  const int rb8 = tid >> 3;                         // f32 path
  const int pb8 = (tid & 7) ^ ((tid >> 3) & 7);
  const char* gBg0; const char* gBu0;
  if constexpr (sizeof(BT) == 2) {
    gBg0 = (const char*)(Bg + (size_t)(n0 + rb4) * DHID) + pb4 * 16;
    gBu0 = (const char*)(Bu + (size_t)(n0 + rb4) * DHID) + pb4 * 16;
  } else {
    gBg0 = (const char*)(Bg + (size_t)(n0 + rb8) * DHID) + pb8 * 16;
    gBu0 = (const char*)(Bu + (size_t)(n0 + rb8) * DHID) + pb8 * 16;
  }

  f32x4 accg[4][4], accu[4][4];
  const f32x4 vz = {0.f, 0.f, 0.f, 0.f};
#pragma unroll
  for (int i = 0; i < 4; ++i)
#pragma unroll
    for (int j = 0; j < 4; ++j) { accg[i][j] = vz; accu[i][j] = vz; }

  for (int kt = 0; kt < DHID; kt += 32) {
    gload16(gA0 + (size_t)kt * 2, sA + tid * 16);
    gload16(gA1 + (size_t)kt * 2, sA + (tid + 256) * 16);
    if constexpr (sizeof(BT) == 2) {
      const size_t step64 = (size_t)64 * DHID * 2;
      gload16(gBg0 + (size_t)kt * 2, sBg + tid * 16);
      gload16(gBg0 + step64 + (size_t)kt * 2, sBg + (tid + 256) * 16);
      gload16(gBu0 + (size_t)kt * 2, sBu + tid * 16);
      gload16(gBu0 + step64 + (size_t)kt * 2, sBu + (tid + 256) * 16);
    } else {
      const size_t bstep = (size_t)32 * DHID * 4;
#pragma unroll
      for (int j = 0; j < 4; ++j) {
        gload16(gBg0 + j * bstep + (size_t)kt * 4, sBg + (tid + j * 256) * 16);
        gload16(gBu0 + j * bstep + (size_t)kt * 4, sBu + (tid + j * 256) * 16);
      }
    }
    __syncthreads();

    bf16x8 af[4];
#pragma unroll
    for (int im = 0; im < 4; ++im) {
      const int r = mw + im * 16 + ln;
      af[im] = *(const bf16x8*)(sA + ((r * 4 + (q4 ^ ((r >> 1) & 3))) << 4));
    }
#pragma unroll
    for (int in_ = 0; in_ < 4; ++in_) {
      const int r = nw + in_ * 16 + ln;
      bf16x8 bg, bu;
      if constexpr (sizeof(BT) == 2) {
        bg = *(const bf16x8*)(sBg + ((r * 4 + (q4 ^ ((r >> 1) & 3))) << 4));
        bu = *(const bf16x8*)(sBu + ((r * 4 + (q4 ^ ((r >> 1) & 3))) << 4));
      } else {
        const int sw = r & 7;
        const float4 g0 = *(const float4*)(sBg + ((r * 8 + ((q4 * 2) ^ sw)) << 4));
        const float4 g1 = *(const float4*)(sBg + ((r * 8 + ((q4 * 2 + 1) ^ sw)) << 4));
        const float4 u0 = *(const float4*)(sBu + ((r * 8 + ((q4 * 2) ^ sw)) << 4));
        const float4 u1 = *(const float4*)(sBu + ((r * 8 + ((q4 * 2 + 1) ^ sw)) << 4));
        bg[0] = (__bf16)g0.x; bg[1] = (__bf16)g0.y; bg[2] = (__bf16)g0.z; bg[3] = (__bf16)g0.w;
        bg[4] = (__bf16)g1.x; bg[5] = (__bf16)g1.y; bg[6] = (__bf16)g1.z; bg[7] = (__bf16)g1.w;
        bu[0] = (__bf16)u0.x; bu[1] = (__bf16)u0.y; bu[2] = (__bf16)u0.z; bu[3] = (__bf16)u0.w;
        bu[4] = (__bf16)u1.x; bu[5] = (__bf16)u1.y; bu[6] = (__bf16)u1.z; bu[7] = (__bf16)u1.w;
      }
#pragma unroll
      for (int im = 0; im < 4; ++im) {
        accg[im][in_] = __builtin_amdgcn_mfma_f32_16x16x32_bf16(af[im], bg, accg[im][in_], 0, 0, 0);
        accu[im][in_] = __builtin_amdgcn_mfma_f32_16x16x32_bf16(af[im], bu, accu[im][in_], 0, 0, 0);
      }
    }
    __syncthreads();
  }

  // epilogue: act = silu(gate) * up -> bf16
#pragma unroll
  for (int im = 0; im < 4; ++im) {
#pragma unroll
    for (int r = 0; r < 4; ++r) {
      const int row = mw + im * 16 + q4 * 4 + r;
      if (m0 + row < cnt) {
        __bf16* dst = act + (size_t)(off + m0 + row) * DHID + n0 + nw + ln;
#pragma unroll
        for (int in_ = 0; in_ < 4; ++in_) {
          const float gg = accg[im][in_][r];
          const float uu = accu[im][in_][r];
          const float a = (gg / (1.0f + __expf(-gg))) * uu;
          dst[in_ * 16] = (__bf16)a;
        }
      }
    }
  }
}

// ---------------- down grouped GEMM ------------------------------------------
// ATOMIC=false: write wt*result to pair-slot buffer (combine_kernel sums later)
// ATOMIC=true : legacy atomicAdd into out (fallback when ws too small)
template <typename BT, bool ATOMIC>
__global__ __launch_bounds__(256) void down_kernel(
    const __bf16* __restrict__ act,
    const BT* __restrict__ dwAll, const BT* __restrict__ sdw,
    float* __restrict__ out, float* __restrict__ buf,
    const int* __restrict__ tok_id, const float* __restrict__ tok_w,
    const int* __restrict__ dst_id,
    const int* __restrict__ cnts, const int* __restrict__ offs,
    const int2* __restrict__ tiles) {
  const int2 tl = tiles[blockIdx.y];
  const int e = tl.x;
  if (e < 0) return;
  const int m0 = tl.y;
  const int cnt = cnts[e];
  const int n0 = blockIdx.x * 128;
  const int off = offs[e];
  const BT* B;
  if (e < NEXP || sdw == nullptr) B = dwAll + (size_t)e * DD; else B = sdw;

  __shared__ __align__(16) char sA[128 * 32 * 2];
  __shared__ __align__(16) char sB[128 * 32 * sizeof(BT)];

  const int tid = threadIdx.x;
  const int lane = tid & 63;
  const int wv = tid >> 6;
  const int mw = (wv >> 1) * 64;
  const int nw = (wv & 1) * 64;
  const int q4 = lane >> 4;
  const int ln = lane & 15;

  const int ra = tid >> 2;
  const int pa = (tid & 3) ^ ((tid >> 3) & 3);
  const char* gA0 = (const char*)(act + (size_t)(off + m0 + ra) * DHID) + pa * 16;
  const char* gA1 = gA0 + (size_t)64 * DHID * 2;

  const int rb4 = tid >> 2;
  const int pb4 = (tid & 3) ^ ((tid >> 3) & 3);
  const int rb8 = tid >> 3;
  const int pb8 = (tid & 7) ^ ((tid >> 3) & 7);
  const char* gB0;
  if constexpr (sizeof(BT) == 2)
    gB0 = (const char*)(B + (size_t)(n0 + rb4) * DHID) + pb4 * 16;
  else
    gB0 = (const char*)(B + (size_t)(n0 + rb8) * DHID) + pb8 * 16;

  f32x4 acc[4][4];
  const f32x4 vz = {0.f, 0.f, 0.f, 0.f};
#pragma unroll
  for (int i = 0; i < 4; ++i)
#pragma unroll
    for (int j = 0; j < 4; ++j) acc[i][j] = vz;

  for (int kt = 0; kt < DHID; kt += 32) {
    gload16(gA0 + (size_t)kt * 2, sA + tid * 16);
    gload16(gA1 + (size_t)kt * 2, sA + (tid + 256) * 16);
    if constexpr (sizeof(BT) == 2) {
      const size_t step64 = (size_t)64 * DHID * 2;
      gload16(gB0 + (size_t)kt * 2, sB + tid * 16);
      gload16(gB0 + step64 + (size_t)kt * 2, sB + (tid + 256) * 16);
    } else {
      const size_t bstep = (size_t)32 * DHID * 4;
#pragma unroll
      for (int j = 0; j < 4; ++j)
        gload16(gB0 + j * bstep + (size_t)kt * 4, sB + (tid + j * 256) * 16);
    }
    __syncthreads();

    bf16x8 af[4];
#pragma unroll
    for (int im = 0; im < 4; ++im) {
      const int r = mw + im * 16 + ln;
      af[im] = *(const bf16x8*)(sA + ((r * 4 + (q4 ^ ((r >> 1) & 3))) << 4));
    }
#pragma unroll
    for (int in_ = 0; in_ < 4; ++in_) {
      const int r = nw + in_ * 16 + ln;
      bf16x8 bb;
      if constexpr (sizeof(BT) == 2) {
        bb = *(const bf16x8*)(sB + ((r * 4 + (q4 ^ ((r >> 1) & 3))) << 4));
      } else {
        const int sw = r & 7;
        const float4 b0 = *(const float4*)(sB + ((r * 8 + ((q4 * 2) ^ sw)) << 4));
        const float4 b1 = *(const float4*)(sB + ((r * 8 + ((q4 * 2 + 1) ^ sw)) << 4));
        bb[0] = (__bf16)b0.x; bb[1] = (__bf16)b0.y; bb[2] = (__bf16)b0.z; bb[3] = (__bf16)b0.w;
        bb[4] = (__bf16)b1.x; bb[5] = (__bf16)b1.y; bb[6] = (__bf16)b1.z; bb[7] = (__bf16)b1.w;
      }
#pragma unroll
      for (int im = 0; im < 4; ++im)
        acc[im][in_] = __builtin_amdgcn_mfma_f32_16x16x32_bf16(af[im], bb, acc[im][in_], 0, 0, 0);
    }
    __syncthreads();
  }

#pragma unroll
  for (int im = 0; im < 4; ++im) {
#pragma unroll
    for (int r = 0; r < 4; ++r) {
      const int row = mw + im * 16 + q4 * 4 + r;
      if (m0 + row < cnt) {
        const int gr = off + m0 + row;
        const float wt = tok_w[gr];
        if constexpr (ATOMIC) {
          const int tok = tok_id[gr];
          float* dst = out + (size_t)tok * DHID + n0 + nw + ln;
#pragma unroll
          for (int in_ = 0; in_ < 4; ++in_)
            atomicAdd(dst + in_ * 16, wt * acc[im][in_][r]);
        } else {
          float* dst = buf + (size_t)dst_id[gr] * DHID + n0 + nw + ln;
#pragma unroll
          for (int in_ = 0; in_ < 4; ++in_)
            dst[in_ * 16] = wt * acc[im][in_][r];
        }
      }
    }
  }
}

// ---------------- combine: out[t] = buf[2t] + buf[2t+1] + buf[NPAIR+t] --------
__global__ void combine_kernel(const float4* __restrict__ buf, float4* __restrict__ out) {
  const int i = blockIdx.x * 256 + threadIdx.x;   // over NTOK*DHID/4 = 1M
  const int t = i >> 9;                           // DHID/4 = 512 float4 per row
  const int d = i & 511;
  const float4 a = buf[(size_t)(2 * t) * 512 + d];
  const float4 b = buf[(size_t)(2 * t + 1) * 512 + d];
  const float4 c = buf[(size_t)(NPAIR + t) * 512 + d];
  float4 r;
  r.x = a.x + b.x + c.x; r.y = a.y + b.y + c.y;
  r.z = a.z + b.z + c.z; r.w = a.w + b.w + c.w;
  out[i] = r;
}

extern "C" void kernel_launch(void* const* d_in, const int* in_sizes, int n_in,
                              void* d_out, int out_size, void* d_ws, size_t ws_size,
                              hipStream_t stream) {
  (void)in_sizes; (void)n_in;
  const float* x   = (const float*)d_in[0];
  const float* wts = (const float*)d_in[1];
  const int*   idx = (const int*)d_in[2];
  const float* gw  = (const float*)d_in[5];
  const float* uw  = (const float*)d_in[6];
  const float* dwn = (const float*)d_in[7];
  const float* sgw = (const float*)d_in[8];
  const float* suw = (const float*)d_in[9];
  const float* sdw = (const float*)d_in[10];
  float* out = (float*)d_out;
  char* ws = (char*)d_ws;

  const size_t WB    = 3 * 9 * DD * 2;              // 216 MiB bf16 weights
  const size_t XBsz  = (size_t)NTOK * DHID * 2;     // 8 MiB
  const size_t ACTsz = (size_t)NROWS * DHID * 2;    // 24 MiB
  const size_t BUFsz = (size_t)NROWS * DHID * 4;    // 48 MiB
  const size_t RTsz  = 131072;

  if (ws_size >= WB + XBsz + ACTsz + BUFsz + RTsz) {
    // Tier A: bf16 weights + buffered combine
    __bf16* wbg = (__bf16*)ws;
    __bf16* wbu = wbg + 9 * DD;
    __bf16* wbd = wbu + 9 * DD;
    __bf16* xb  = (__bf16*)(ws + WB);
    __bf16* act = (__bf16*)(ws + WB + XBsz);
    float*  buf = (float*)(ws + WB + XBsz + ACTsz);
    char*   rt  = ws + WB + XBsz + ACTsz + BUFsz;
    int*   tok_id = (int*)rt;
    float* tok_w  = (float*)(rt + NROWS * 4);
    int*   dst_id = (int*)(rt + NROWS * 8);
    int*   cnts   = (int*)(rt + NROWS * 12);
    int*   offs   = cnts + 16;
    int2*  tiles  = (int2*)(offs + 16);

    route_kernel<<<1, 256, 0, stream>>>(idx, wts, tok_id, tok_w, dst_id, cnts, offs, tiles);
    cast_kernel<<<2048, 256, 0, stream>>>((const float4*)x, (bf16x8*)xb);
    cast_kernel<<<16384, 256, 0, stream>>>((const float4*)gw, (bf16x8*)wbg);
    cast_kernel<<<2048, 256, 0, stream>>>((const float4*)sgw, (bf16x8*)(wbg + 8 * DD));
    cast_kernel<<<16384, 256, 0, stream>>>((const float4*)uw, (bf16x8*)wbu);
    cast_kernel<<<2048, 256, 0, stream>>>((const float4*)suw, (bf16x8*)(wbu + 8 * DD));
    cast_kernel<<<16384, 256, 0, stream>>>((const float4*)dwn, (bf16x8*)wbd);
    cast_kernel<<<2048, 256, 0, stream>>>((const float4*)sdw, (bf16x8*)(wbd + 8 * DD));
    gateup_kernel<__bf16><<<dim3(16, MAXTILES), 256, 0, stream>>>(
        xb, wbg, wbu, nullptr, nullptr, act, tok_id, cnts, offs, tiles);
    down_kernel<__bf16, false><<<dim3(16, MAXTILES), 256, 0, stream>>>(
        act, wbd, nullptr, out, buf, tok_id, tok_w, dst_id, cnts, offs, tiles);
    combine_kernel<<<4096, 256, 0, stream>>>((const float4*)buf, (float4*)out);
  } else if (ws_size >= XBsz + ACTsz + BUFsz + RTsz) {
    // Tier B: f32 weights from LDS + buffered combine
    __bf16* xb  = (__bf16*)ws;
    __bf16* act = (__bf16*)(ws + XBsz);
    float*  buf = (float*)(ws + XBsz + ACTsz);
    char*   rt  = ws + XBsz + ACTsz + BUFsz;
    int*   tok_id = (int*)rt;
    float* tok_w  = (float*)(rt + NROWS * 4);
    int*   dst_id = (int*)(rt + NROWS * 8);
    int*   cnts   = (int*)(rt + NROWS * 12);
    int*   offs   = cnts + 16;
    int2*  tiles  = (int2*)(offs + 16);

    route_kernel<<<1, 256, 0, stream>>>(idx, wts, tok_id, tok_w, dst_id, cnts, offs, tiles);
    cast_kernel<<<2048, 256, 0, stream>>>((const float4*)x, (bf16x8*)xb);
    gateup_kernel<float><<<dim3(16, MAXTILES), 256, 0, stream>>>(
        xb, gw, uw, sgw, suw, act, tok_id, cnts, offs, tiles);
    down_kernel<float, false><<<dim3(16, MAXTILES), 256, 0, stream>>>(
        act, dwn, sdw, out, buf, tok_id, tok_w, dst_id, cnts, offs, tiles);
    combine_kernel<<<4096, 256, 0, stream>>>((const float4*)buf, (float4*)out);
  } else {
    // Tier C: f32 weights + atomic scatter (round-1 behavior)
    __bf16* xb  = (__bf16*)ws;
    __bf16* act = (__bf16*)(ws + XBsz);
    char*   rt  = ws + XBsz + ACTsz;
    int*   tok_id = (int*)rt;
    float* tok_w  = (float*)(rt + NROWS * 4);
    int*   dst_id = (int*)(rt + NROWS * 8);
    int*   cnts   = (int*)(rt + NROWS * 12);
    int*   offs   = cnts + 16;
    int2*  tiles  = (int2*)(offs + 16);

    (void)hipMemsetAsync(d_out, 0, (size_t)out_size * sizeof(float), stream);
    route_kernel<<<1, 256, 0, stream>>>(idx, wts, tok_id, tok_w, dst_id, cnts, offs, tiles);
    cast_kernel<<<2048, 256, 0, stream>>>((const float4*)x, (bf16x8*)xb);
    gateup_kernel<float><<<dim3(16, MAXTILES), 256, 0, stream>>>(
        xb, gw, uw, sgw, suw, act, tok_id, cnts, offs, tiles);
    down_kernel<float, true><<<dim3(16, MAXTILES), 256, 0, stream>>>(
        act, dwn, sdw, out, nullptr, tok_id, tok_w, dst_id, cnts, offs, tiles);
  }
}

// Round 3
// 661.844 us; speedup vs baseline: 1.2792x; 1.2543x over previous
//
#include <hip/hip_runtime.h>
#include <cstdint>
#include <cstddef>

// Problem constants (G=2,S=1024,D=2048,E=8,K=2)
#define DHID 2048
#define NEXP 8
#define NTOK 2048            // G*S tokens
#define NPAIR 4096           // NTOK*K routed pairs
#define NROWS 6144           // NPAIR + NTOK (shared expert appended)
#define MAXTILES 55          // worst-case routed m-tiles (39) + shared (16)
#define DD ((size_t)DHID * DHID)

typedef __attribute__((ext_vector_type(8))) __bf16 bf16x8;
typedef __attribute__((ext_vector_type(4))) float f32x4;

typedef __attribute__((address_space(3))) void lds_void;
typedef __attribute__((address_space(1))) void gbl_void;

__device__ __forceinline__ void gload16(const void* g, void* l) {
  __builtin_amdgcn_global_load_lds((gbl_void*)g, (lds_void*)l, 16, 0, 0);
}

// ---------------- routing: bucket pairs by expert, append shared pseudo-expert,
// ---------------- build (expert, m0) tile list for flattened GEMM grids -------
__global__ void route_kernel(const int* __restrict__ idx, const float* __restrict__ wts,
                             int* __restrict__ tok_id, float* __restrict__ tok_w,
                             int* __restrict__ dst_id,
                             int* __restrict__ cnts, int* __restrict__ offs,
                             int2* __restrict__ tiles) {
  __shared__ int c[NEXP];
  __shared__ int cur[NEXP];
  const int t = threadIdx.x;
  if (t < NEXP) c[t] = 0;
  __syncthreads();
  for (int p = t; p < NPAIR; p += 256) atomicAdd(&c[idx[p]], 1);
  __syncthreads();
  if (t == 0) {
    int run = 0;
    for (int e = 0; e < NEXP; ++e) { cur[e] = run; offs[e] = run; cnts[e] = c[e]; run += c[e]; }
    offs[NEXP] = NPAIR; cnts[NEXP] = NTOK;
    int nt = 0;
    for (int e = 0; e <= NEXP; ++e) {
      const int ce = (e < NEXP) ? c[e] : NTOK;
      for (int m0 = 0; m0 < ce; m0 += 128) { tiles[nt].x = e; tiles[nt].y = m0; ++nt; }
    }
    for (; nt < MAXTILES; ++nt) { tiles[nt].x = -1; tiles[nt].y = 0; }
  }
  __syncthreads();
  for (int p = t; p < NPAIR; p += 256) {
    const int e = idx[p];
    const int slot = atomicAdd(&cur[e], 1);
    tok_id[slot] = p >> 1;          // K=2: token = pair/2 (flat g*S+s)
    tok_w[slot] = wts[p];
    dst_id[slot] = p;               // pair-slot row in combine buffer
  }
  for (int i = t; i < NTOK; i += 256) {
    tok_id[NPAIR + i] = i; tok_w[NPAIR + i] = 1.0f; dst_id[NPAIR + i] = NPAIR + i;
  }
}

// ---------------- fused f32 -> bf16 cast of ALL tensors (one dispatch) --------
// dst linear layout (chunks of 8 elems): gw(8L) sgw(L) uw(8L) suw(L) dwn(8L) sdw(L) x(L)
// where L = DD/8 = 524288 chunks. Total 28L chunks = 57344 blocks * 256.
__global__ void cast_all_kernel(const float4* __restrict__ gw, const float4* __restrict__ sgw,
                                const float4* __restrict__ uw, const float4* __restrict__ suw,
                                const float4* __restrict__ dwn, const float4* __restrict__ sdw,
                                const float4* __restrict__ x, bf16x8* __restrict__ dst) {
  const size_t L = DD / 8;
  const size_t i = (size_t)blockIdx.x * 256 + threadIdx.x;
  size_t r = i;
  const float4* src;
  if (r < 8 * L) { src = gw; }
  else if ((r -= 8 * L) < L) { src = sgw; }
  else if ((r -= L) < 8 * L) { src = uw; }
  else if ((r -= 8 * L) < L) { src = suw; }
  else if ((r -= L) < 8 * L) { src = dwn; }
  else if ((r -= 8 * L) < L) { src = sdw; }
  else { r -= L; src = x; }
  const float4 a = src[2 * r];
  const float4 b = src[2 * r + 1];
  bf16x8 o;
  o[0] = (__bf16)a.x; o[1] = (__bf16)a.y; o[2] = (__bf16)a.z; o[3] = (__bf16)a.w;
  o[4] = (__bf16)b.x; o[5] = (__bf16)b.y; o[6] = (__bf16)b.z; o[7] = (__bf16)b.w;
  dst[i] = o;
}

// ---------------- fused gate+up grouped GEMM + SiLU ---------------------------
// Block tile 128(m) x 64(n), BK=64. 4 waves, wave tile 64x32.
// acc = 2 outputs x 4x2 f32x4 = 64 AGPR/wave -> 3 blocks/CU.
__global__ __launch_bounds__(256, 3) void gateup_kernel(
    const __bf16* __restrict__ xb,
    const __bf16* __restrict__ wbg, const __bf16* __restrict__ wbu,
    __bf16* __restrict__ act,
    const int* __restrict__ tok_id,
    const int* __restrict__ cnts, const int* __restrict__ offs,
    const int2* __restrict__ tiles) {
  const int2 tl = tiles[blockIdx.y];
  const int e = tl.x;
  if (e < 0) return;
  const int m0 = tl.y;
  const int cnt = cnts[e];
  const int n0 = blockIdx.x * 64;
  const int off = offs[e];
  const __bf16* Bg = wbg + (size_t)e * DD;
  const __bf16* Bu = wbu + (size_t)e * DD;

  __shared__ __align__(16) char sA[128 * 64 * 2];   // 16 KB: bf16 [128][64]
  __shared__ __align__(16) char sBg[64 * 64 * 2];   // 8 KB
  __shared__ __align__(16) char sBu[64 * 64 * 2];   // 8 KB

  const int tid = threadIdx.x;
  const int lane = tid & 63;
  const int wv = tid >> 6;
  const int mw = (wv >> 1) * 64;
  const int nw = (wv & 1) * 32;
  const int q4 = lane >> 4;
  const int ln = lane & 15;

  // Staging: chunk q = tid + j*256 -> row q>>3 (A: [0,128), B: [0,64)),
  // LDS dest is LINEAR (q*16); the GLOBAL source part is permuted:
  // part p = (tid&7) ^ ((tid>>3)&7)  (row&7 invariant across j since rows step by 32)
  const int rbase = tid >> 3;
  const int part = (tid & 7) ^ (rbase & 7);

  const char* gA[4];
#pragma unroll
  for (int j = 0; j < 4; ++j) {
    int r = m0 + rbase + 32 * j;
    r = (r < cnt) ? r : (cnt - 1);
    gA[j] = (const char*)(xb + (size_t)tok_id[off + r] * DHID) + part * 16;
  }
  const char* gBg[2]; const char* gBu[2];
#pragma unroll
  for (int j = 0; j < 2; ++j) {
    gBg[j] = (const char*)(Bg + (size_t)(n0 + rbase + 32 * j) * DHID) + part * 16;
    gBu[j] = (const char*)(Bu + (size_t)(n0 + rbase + 32 * j) * DHID) + part * 16;
  }

  f32x4 accg[4][2], accu[4][2];
  const f32x4 vz = {0.f, 0.f, 0.f, 0.f};
#pragma unroll
  for (int i = 0; i < 4; ++i)
#pragma unroll
    for (int j = 0; j < 2; ++j) { accg[i][j] = vz; accu[i][j] = vz; }

  for (int kt = 0; kt < DHID; kt += 64) {
#pragma unroll
    for (int j = 0; j < 4; ++j)
      gload16(gA[j] + (size_t)kt * 2, sA + (tid + j * 256) * 16);
#pragma unroll
    for (int j = 0; j < 2; ++j) {
      gload16(gBg[j] + (size_t)kt * 2, sBg + (tid + j * 256) * 16);
      gload16(gBu[j] + (size_t)kt * 2, sBu + (tid + j * 256) * 16);
    }
    __syncthreads();

#pragma unroll
    for (int h = 0; h < 2; ++h) {
      bf16x8 af[4];
#pragma unroll
      for (int im = 0; im < 4; ++im) {
        const int r = mw + im * 16 + ln;
        af[im] = *(const bf16x8*)(sA + ((r * 8 + ((q4 + 4 * h) ^ (r & 7))) << 4));
      }
#pragma unroll
      for (int in_ = 0; in_ < 2; ++in_) {
        const int r = nw + in_ * 16 + ln;
        const int c = (r * 8 + ((q4 + 4 * h) ^ (r & 7))) << 4;
        const bf16x8 bg = *(const bf16x8*)(sBg + c);
        const bf16x8 bu = *(const bf16x8*)(sBu + c);
#pragma unroll
        for (int im = 0; im < 4; ++im) {
          accg[im][in_] = __builtin_amdgcn_mfma_f32_16x16x32_bf16(af[im], bg, accg[im][in_], 0, 0, 0);
          accu[im][in_] = __builtin_amdgcn_mfma_f32_16x16x32_bf16(af[im], bu, accu[im][in_], 0, 0, 0);
        }
      }
    }
    __syncthreads();
  }

  // epilogue: act = silu(gate) * up -> bf16
#pragma unroll
  for (int im = 0; im < 4; ++im) {
#pragma unroll
    for (int rr = 0; rr < 4; ++rr) {
      const int row = mw + im * 16 + q4 * 4 + rr;
      if (m0 + row < cnt) {
        __bf16* dst = act + (size_t)(off + m0 + row) * DHID + n0 + nw + ln;
#pragma unroll
        for (int in_ = 0; in_ < 2; ++in_) {
          const float gg = accg[im][in_][rr];
          const float uu = accu[im][in_][rr];
          const float a = (gg / (1.0f + __expf(-gg))) * uu;
          dst[in_ * 16] = (__bf16)a;
        }
      }
    }
  }
}

// ---------------- down grouped GEMM, weighted write to pair-slot buffer -------
// Block tile 128(m) x 64(n), BK=64, wave tile 64x32, acc 4x2 f32x4 = 32 AGPR.
__global__ __launch_bounds__(256, 3) void down_kernel(
    const __bf16* __restrict__ act,
    const __bf16* __restrict__ wbd,
    float* __restrict__ buf,
    const float* __restrict__ tok_w, const int* __restrict__ dst_id,
    const int* __restrict__ cnts, const int* __restrict__ offs,
    const int2* __restrict__ tiles) {
  const int2 tl = tiles[blockIdx.y];
  const int e = tl.x;
  if (e < 0) return;
  const int m0 = tl.y;
  const int cnt = cnts[e];
  const int n0 = blockIdx.x * 64;
  const int off = offs[e];
  const __bf16* B = wbd + (size_t)e * DD;

  __shared__ __align__(16) char sA[128 * 64 * 2];   // 16 KB
  __shared__ __align__(16) char sB[64 * 64 * 2];    // 8 KB

  const int tid = threadIdx.x;
  const int lane = tid & 63;
  const int wv = tid >> 6;
  const int mw = (wv >> 1) * 64;
  const int nw = (wv & 1) * 32;
  const int q4 = lane >> 4;
  const int ln = lane & 15;

  const int rbase = tid >> 3;
  const int part = (tid & 7) ^ (rbase & 7);

  const char* gA[4];
#pragma unroll
  for (int j = 0; j < 4; ++j)
    gA[j] = (const char*)(act + (size_t)(off + m0 + rbase + 32 * j) * DHID) + part * 16;
  const char* gB[2];
#pragma unroll
  for (int j = 0; j < 2; ++j)
    gB[j] = (const char*)(B + (size_t)(n0 + rbase + 32 * j) * DHID) + part * 16;

  f32x4 acc[4][2];
  const f32x4 vz = {0.f, 0.f, 0.f, 0.f};
#pragma unroll
  for (int i = 0; i < 4; ++i)
#pragma unroll
    for (int j = 0; j < 2; ++j) acc[i][j] = vz;

  for (int kt = 0; kt < DHID; kt += 64) {
#pragma unroll
    for (int j = 0; j < 4; ++j)
      gload16(gA[j] + (size_t)kt * 2, sA + (tid + j * 256) * 16);
#pragma unroll
    for (int j = 0; j < 2; ++j)
      gload16(gB[j] + (size_t)kt * 2, sB + (tid + j * 256) * 16);
    __syncthreads();

#pragma unroll
    for (int h = 0; h < 2; ++h) {
      bf16x8 af[4];
#pragma unroll
      for (int im = 0; im < 4; ++im) {
        const int r = mw + im * 16 + ln;
        af[im] = *(const bf16x8*)(sA + ((r * 8 + ((q4 + 4 * h) ^ (r & 7))) << 4));
      }
#pragma unroll
      for (int in_ = 0; in_ < 2; ++in_) {
        const int r = nw + in_ * 16 + ln;
        const bf16x8 bb = *(const bf16x8*)(sB + ((r * 8 + ((q4 + 4 * h) ^ (r & 7))) << 4));
#pragma unroll
        for (int im = 0; im < 4; ++im)
          acc[im][in_] = __builtin_amdgcn_mfma_f32_16x16x32_bf16(af[im], bb, acc[im][in_], 0, 0, 0);
      }
    }
    __syncthreads();
  }

#pragma unroll
  for (int im = 0; im < 4; ++im) {
#pragma unroll
    for (int rr = 0; rr < 4; ++rr) {
      const int row = mw + im * 16 + q4 * 4 + rr;
      if (m0 + row < cnt) {
        const int gr = off + m0 + row;
        const float wt = tok_w[gr];
        float* dst = buf + (size_t)dst_id[gr] * DHID + n0 + nw + ln;
#pragma unroll
        for (int in_ = 0; in_ < 2; ++in_)
          dst[in_ * 16] = wt * acc[im][in_][rr];
      }
    }
  }
}

// ---------------- combine: out[t] = buf[2t] + buf[2t+1] + buf[NPAIR+t] --------
__global__ void combine_kernel(const float4* __restrict__ buf, float4* __restrict__ out) {
  const int i = blockIdx.x * 256 + threadIdx.x;   // over NTOK*DHID/4 = 1M
  const int t = i >> 9;                           // DHID/4 = 512 float4 per row
  const int d = i & 511;
  const float4 a = buf[(size_t)(2 * t) * 512 + d];
  const float4 b = buf[(size_t)(2 * t + 1) * 512 + d];
  const float4 c = buf[(size_t)(NPAIR + t) * 512 + d];
  float4 r;
  r.x = a.x + b.x + c.x; r.y = a.y + b.y + c.y;
  r.z = a.z + b.z + c.z; r.w = a.w + b.w + c.w;
  out[i] = r;
}

extern "C" void kernel_launch(void* const* d_in, const int* in_sizes, int n_in,
                              void* d_out, int out_size, void* d_ws, size_t ws_size,
                              hipStream_t stream) {
  (void)in_sizes; (void)n_in; (void)out_size; (void)ws_size;
  const float* x   = (const float*)d_in[0];
  const float* wts = (const float*)d_in[1];
  const int*   idx = (const int*)d_in[2];
  const float* gw  = (const float*)d_in[5];
  const float* uw  = (const float*)d_in[6];
  const float* dwn = (const float*)d_in[7];
  const float* sgw = (const float*)d_in[8];
  const float* suw = (const float*)d_in[9];
  const float* sdw = (const float*)d_in[10];
  float* out = (float*)d_out;
  char* ws = (char*)d_ws;

  // ws layout (~296.1 MiB):
  //   [0)        wbg bf16 [9][DD]   (8 experts + shared)   72 MiB
  //   wbu, wbd   same                                      144 MiB
  //   xb  bf16 [NTOK][DHID]                                8 MiB
  //   act bf16 [NROWS][DHID]                               24 MiB
  //   buf f32  [NROWS][DHID]                               48 MiB
  //   route tables                                         128 KiB
  const size_t WB    = 3 * 9 * DD * 2;
  const size_t XBsz  = (size_t)NTOK * DHID * 2;
  const size_t ACTsz = (size_t)NROWS * DHID * 2;
  const size_t BUFsz = (size_t)NROWS * DHID * 4;

  __bf16* wbg = (__bf16*)ws;
  __bf16* wbu = wbg + 9 * DD;
  __bf16* wbd = wbu + 9 * DD;
  __bf16* xb  = (__bf16*)(ws + WB);
  __bf16* act = (__bf16*)(ws + WB + XBsz);
  float*  buf = (float*)(ws + WB + XBsz + ACTsz);
  char*   rt  = ws + WB + XBsz + ACTsz + BUFsz;
  int*   tok_id = (int*)rt;
  float* tok_w  = (float*)(rt + NROWS * 4);
  int*   dst_id = (int*)(rt + NROWS * 8);
  int*   cnts   = (int*)(rt + NROWS * 12);
  int*   offs   = cnts + 16;
  int2*  tiles  = (int2*)(offs + 16);

  route_kernel<<<1, 256, 0, stream>>>(idx, wts, tok_id, tok_w, dst_id, cnts, offs, tiles);
  // dst order matches ws layout: [gw|sgw][uw|suw][dwn|sdw][x]
  cast_all_kernel<<<57344, 256, 0, stream>>>((const float4*)gw, (const float4*)sgw,
                                             (const float4*)uw, (const float4*)suw,
                                             (const float4*)dwn, (const float4*)sdw,
                                             (const float4*)x, (bf16x8*)ws);
  gateup_kernel<<<dim3(32, MAXTILES), 256, 0, stream>>>(
      xb, wbg, wbu, act, tok_id, cnts, offs, tiles);
  down_kernel<<<dim3(32, MAXTILES), 256, 0, stream>>>(
      act, wbd, buf, tok_w, dst_id, cnts, offs, tiles);
  combine_kernel<<<4096, 256, 0, stream>>>((const float4*)buf, (float4*)out);
}